// Round 2
// baseline (478.479 us; speedup 1.0000x reference)
//
#include <hip/hip_runtime.h>
#include <math.h>

// BiologicalPopulationVectorDecoder — memory-bound reduction. (Retry: rounds
// 0-1 failed on GPU broker capacity, never ran.)
// Pass 1: grid-stride float4 reduction of 8 sums (4 action_activations,
//         4 tuning_contributions) -> per-block partials in d_ws.
// Pass 2: single block reduces partials, applies competition + softmaxes,
//         writes the [5,4]=20-float output.
// Traffic: 28 B/neuron * 16.7M = 470 MB read -> HBM-bound, floor ~75 us.

__device__ __forceinline__ void wave_block_reduce8(float v[8], float* out8) {
    // 64-lane wave reduce for each of the 8 values
    #pragma unroll
    for (int k = 0; k < 8; ++k) {
        #pragma unroll
        for (int off = 32; off > 0; off >>= 1) {
            v[k] += __shfl_down(v[k], off);
        }
    }
    __shared__ float smem[4][8];   // up to 4 waves (256 threads)
    const int wid  = threadIdx.x >> 6;
    const int lane = threadIdx.x & 63;
    if (lane == 0) {
        #pragma unroll
        for (int k = 0; k < 8; ++k) smem[wid][k] = v[k];
    }
    __syncthreads();
    if (threadIdx.x == 0) {
        const int nw = (blockDim.x + 63) >> 6;
        #pragma unroll
        for (int k = 0; k < 8; ++k) {
            float s = 0.f;
            for (int w = 0; w < nw; ++w) s += smem[w][k];
            out8[k] = s;
        }
    }
}

__global__ __launch_bounds__(256) void pvd_reduce_kernel(
    const float* __restrict__ act,
    const float* __restrict__ W,    // [N,4] row-major
    const float* __restrict__ pd,
    const float* __restrict__ tw,
    float* __restrict__ partials,   // [gridDim.x][8]
    int n4)                         // N/4
{
    const float4* act4 = reinterpret_cast<const float4*>(act);
    const float4* pd4  = reinterpret_cast<const float4*>(pd);
    const float4* tw4  = reinterpret_cast<const float4*>(tw);
    const float4* W4   = reinterpret_cast<const float4*>(W);  // one float4 = one neuron's 4 weights

    // action angles (arange(4)/4 * 2pi), rounded to f32
    const float kAng[4] = {0.0f,
                           1.57079632679489662f,
                           3.14159265358979324f,
                           4.71238898038468986f};

    float aa[4] = {0.f, 0.f, 0.f, 0.f};
    float tc[4] = {0.f, 0.f, 0.f, 0.f};

    const int stride = gridDim.x * blockDim.x;
    for (int i = blockIdx.x * blockDim.x + threadIdx.x; i < n4; i += stride) {
        const float4 a4 = act4[i];
        const float4 p4 = pd4[i];
        const float4 t4 = tw4[i];
        const float av[4] = {a4.x, a4.y, a4.z, a4.w};
        const float pv[4] = {p4.x, p4.y, p4.z, p4.w};
        const float tv[4] = {t4.x, t4.y, t4.z, t4.w};
        #pragma unroll
        for (int j = 0; j < 4; ++j) {
            const float4 w4 = W4[4 * i + j];
            const float wv[4] = {w4.x, w4.y, w4.z, w4.w};
            const float a   = (av[j] > 0.001f) ? av[j] : 0.0f;
            const float inv = 1.0f / tv[j];
            #pragma unroll
            for (int r = 0; r < 4; ++r) {
                aa[r] = fmaf(a, wv[r], aa[r]);
                const float arg = (kAng[r] - pv[j]) * inv;
                tc[r] = fmaf(a, __cosf(arg), tc[r]);
            }
        }
    }

    float v[8] = {aa[0], aa[1], aa[2], aa[3], tc[0], tc[1], tc[2], tc[3]};
    float out8[8];
    wave_block_reduce8(v, out8);
    if (threadIdx.x == 0) {
        #pragma unroll
        for (int k = 0; k < 8; ++k) partials[blockIdx.x * 8 + k] = out8[k];
    }
}

__global__ __launch_bounds__(256) void pvd_finalize_kernel(
    const float* __restrict__ partials, int nb,
    const float* __restrict__ Cw,    // [4,4]
    const float* __restrict__ inh,   // scalar
    float* __restrict__ out)         // [5,4]
{
    float v[8] = {0.f, 0.f, 0.f, 0.f, 0.f, 0.f, 0.f, 0.f};
    for (int row = threadIdx.x; row < nb; row += blockDim.x) {
        #pragma unroll
        for (int k = 0; k < 8; ++k) v[k] += partials[row * 8 + k];
    }
    float tot[8];
    wave_block_reduce8(v, tot);

    if (threadIdx.x == 0) {
        float aa[4], tc[4], comb[4], comp[4];
        #pragma unroll
        for (int r = 0; r < 4; ++r) { aa[r] = tot[r]; tc[r] = tot[4 + r]; }
        #pragma unroll
        for (int r = 0; r < 4; ++r) comb[r] = 2.0f * aa[r] + 0.5f * tc[r];

        const float s = *inh;
        #pragma unroll
        for (int a = 0; a < 4; ++a) {
            float m = 0.f;
            #pragma unroll
            for (int b = 0; b < 4; ++b) m += Cw[a * 4 + b] * comb[b];
            comp[a] = comb[a] - s * m;
        }

        // softmax(comb)
        float mx = fmaxf(fmaxf(comb[0], comb[1]), fmaxf(comb[2], comb[3]));
        float e[4], den = 0.f;
        #pragma unroll
        for (int a = 0; a < 4; ++a) { e[a] = __expf(comb[a] - mx); den += e[a]; }
        #pragma unroll
        for (int a = 0; a < 4; ++a) out[a] = e[a] / den;

        // softmax(comp * 3.0)
        float c3[4];
        #pragma unroll
        for (int a = 0; a < 4; ++a) c3[a] = comp[a] * 3.0f;
        mx = fmaxf(fmaxf(c3[0], c3[1]), fmaxf(c3[2], c3[3]));
        den = 0.f;
        #pragma unroll
        for (int a = 0; a < 4; ++a) { e[a] = __expf(c3[a] - mx); den += e[a]; }
        #pragma unroll
        for (int a = 0; a < 4; ++a) out[4 + a] = e[a] / den;

        #pragma unroll
        for (int a = 0; a < 4; ++a) out[8 + a]  = comp[a];
        #pragma unroll
        for (int a = 0; a < 4; ++a) out[12 + a] = aa[a];
        #pragma unroll
        for (int a = 0; a < 4; ++a) out[16 + a] = tc[a];
    }
}

extern "C" void kernel_launch(void* const* d_in, const int* in_sizes, int n_in,
                              void* d_out, int out_size, void* d_ws, size_t ws_size,
                              hipStream_t stream) {
    const float* act = (const float*)d_in[0];
    const float* W   = (const float*)d_in[1];
    const float* pd  = (const float*)d_in[2];
    const float* tw  = (const float*)d_in[3];
    const float* Cw  = (const float*)d_in[4];
    const float* inh = (const float*)d_in[5];
    float* out = (float*)d_out;

    const int N  = in_sizes[0];
    const int n4 = N / 4;

    int nb = 2048;  // 256 CUs x 8 blocks/CU of 256 threads = full occupancy
    const size_t need = (size_t)nb * 8 * sizeof(float);
    if (ws_size < need) nb = (int)(ws_size / (8 * sizeof(float)));
    if (nb < 1) nb = 1;

    float* partials = (float*)d_ws;

    pvd_reduce_kernel<<<nb, 256, 0, stream>>>(act, W, pd, tw, partials, n4);
    pvd_finalize_kernel<<<1, 256, 0, stream>>>(partials, nb, Cw, inh, out);
}

// Round 3
// 453.150 us; speedup vs baseline: 1.0559x; 1.0559x over previous
//
#include <hip/hip_runtime.h>
#include <math.h>

// BiologicalPopulationVectorDecoder — memory-bound reduction (470 MB read).
// R2 measured dur_us=478 total; rocprof top-5 is all harness 1GB re-poison
// fills (~160us) => our reduce kernel < 159us vs 71us HBM floor.
// R3 change: one-neuron-per-thread so ALL streams are perfectly coalesced
// (act/pd/tw: 4B/lane contiguous; W: 16B/lane dwordx4 contiguous) — removes
// the 64B lane-stride W pattern that could 4x the L1->L2 traffic. Also
// nontemporal (evict-first) loads for the read-once streams.
// Pass 1: grid-stride reduction of 8 sums -> per-block partials in d_ws.
// Pass 2: single block reduces partials, competition + softmaxes -> [5,4].

typedef float f32x4 __attribute__((ext_vector_type(4)));

__device__ __forceinline__ void wave_block_reduce8(float v[8], float* out8) {
    #pragma unroll
    for (int k = 0; k < 8; ++k) {
        #pragma unroll
        for (int off = 32; off > 0; off >>= 1) {
            v[k] += __shfl_down(v[k], off);
        }
    }
    __shared__ float smem[4][8];   // up to 4 waves (256 threads)
    const int wid  = threadIdx.x >> 6;
    const int lane = threadIdx.x & 63;
    if (lane == 0) {
        #pragma unroll
        for (int k = 0; k < 8; ++k) smem[wid][k] = v[k];
    }
    __syncthreads();
    if (threadIdx.x == 0) {
        const int nw = (blockDim.x + 63) >> 6;
        #pragma unroll
        for (int k = 0; k < 8; ++k) {
            float s = 0.f;
            for (int w = 0; w < nw; ++w) s += smem[w][k];
            out8[k] = s;
        }
    }
}

__global__ __launch_bounds__(256) void pvd_reduce_kernel(
    const float* __restrict__ act,
    const f32x4* __restrict__ W4,   // [N] rows of 4 weights, one per neuron
    const float* __restrict__ pd,
    const float* __restrict__ tw,
    float* __restrict__ partials,   // [gridDim.x][8]
    int n)                          // N neurons
{
    // action angles (arange(4)/4 * 2pi), rounded to f32
    const float kAng[4] = {0.0f,
                           1.57079632679489662f,
                           3.14159265358979324f,
                           4.71238898038468986f};

    float aa[4] = {0.f, 0.f, 0.f, 0.f};
    float tc[4] = {0.f, 0.f, 0.f, 0.f};

    const int stride = gridDim.x * blockDim.x;
    for (int i = blockIdx.x * blockDim.x + threadIdx.x; i < n; i += stride) {
        const float a0 = __builtin_nontemporal_load(act + i);
        const float p  = __builtin_nontemporal_load(pd + i);
        const float t  = __builtin_nontemporal_load(tw + i);
        const f32x4 w  = __builtin_nontemporal_load(W4 + i);

        const float a   = (a0 > 0.001f) ? a0 : 0.0f;
        const float inv = 1.0f / t;

        aa[0] = fmaf(a, w.x, aa[0]);
        aa[1] = fmaf(a, w.y, aa[1]);
        aa[2] = fmaf(a, w.z, aa[2]);
        aa[3] = fmaf(a, w.w, aa[3]);
        #pragma unroll
        for (int r = 0; r < 4; ++r) {
            const float arg = (kAng[r] - p) * inv;
            tc[r] = fmaf(a, __cosf(arg), tc[r]);
        }
    }

    float v[8] = {aa[0], aa[1], aa[2], aa[3], tc[0], tc[1], tc[2], tc[3]};
    float out8[8];
    wave_block_reduce8(v, out8);
    if (threadIdx.x == 0) {
        #pragma unroll
        for (int k = 0; k < 8; ++k) partials[blockIdx.x * 8 + k] = out8[k];
    }
}

__global__ __launch_bounds__(256) void pvd_finalize_kernel(
    const float* __restrict__ partials, int nb,
    const float* __restrict__ Cw,    // [4,4]
    const float* __restrict__ inh,   // scalar
    float* __restrict__ out)         // [5,4]
{
    float v[8] = {0.f, 0.f, 0.f, 0.f, 0.f, 0.f, 0.f, 0.f};
    for (int row = threadIdx.x; row < nb; row += blockDim.x) {
        #pragma unroll
        for (int k = 0; k < 8; ++k) v[k] += partials[row * 8 + k];
    }
    float tot[8];
    wave_block_reduce8(v, tot);

    if (threadIdx.x == 0) {
        float aa[4], tc[4], comb[4], comp[4];
        #pragma unroll
        for (int r = 0; r < 4; ++r) { aa[r] = tot[r]; tc[r] = tot[4 + r]; }
        #pragma unroll
        for (int r = 0; r < 4; ++r) comb[r] = 2.0f * aa[r] + 0.5f * tc[r];

        const float s = *inh;
        #pragma unroll
        for (int a = 0; a < 4; ++a) {
            float m = 0.f;
            #pragma unroll
            for (int b = 0; b < 4; ++b) m += Cw[a * 4 + b] * comb[b];
            comp[a] = comb[a] - s * m;
        }

        // softmax(comb)
        float mx = fmaxf(fmaxf(comb[0], comb[1]), fmaxf(comb[2], comb[3]));
        float e[4], den = 0.f;
        #pragma unroll
        for (int a = 0; a < 4; ++a) { e[a] = __expf(comb[a] - mx); den += e[a]; }
        #pragma unroll
        for (int a = 0; a < 4; ++a) out[a] = e[a] / den;

        // softmax(comp * 3.0)
        float c3[4];
        #pragma unroll
        for (int a = 0; a < 4; ++a) c3[a] = comp[a] * 3.0f;
        mx = fmaxf(fmaxf(c3[0], c3[1]), fmaxf(c3[2], c3[3]));
        den = 0.f;
        #pragma unroll
        for (int a = 0; a < 4; ++a) { e[a] = __expf(c3[a] - mx); den += e[a]; }
        #pragma unroll
        for (int a = 0; a < 4; ++a) out[4 + a] = e[a] / den;

        #pragma unroll
        for (int a = 0; a < 4; ++a) out[8 + a]  = comp[a];
        #pragma unroll
        for (int a = 0; a < 4; ++a) out[12 + a] = aa[a];
        #pragma unroll
        for (int a = 0; a < 4; ++a) out[16 + a] = tc[a];
    }
}

extern "C" void kernel_launch(void* const* d_in, const int* in_sizes, int n_in,
                              void* d_out, int out_size, void* d_ws, size_t ws_size,
                              hipStream_t stream) {
    const float* act = (const float*)d_in[0];
    const f32x4* W4  = (const f32x4*)d_in[1];
    const float* pd  = (const float*)d_in[2];
    const float* tw  = (const float*)d_in[3];
    const float* Cw  = (const float*)d_in[4];
    const float* inh = (const float*)d_in[5];
    float* out = (float*)d_out;

    const int N = in_sizes[0];

    int nb = 2048;  // 256 CUs x 8 blocks/CU of 256 threads
    const size_t need = (size_t)nb * 8 * sizeof(float);
    if (ws_size < need) nb = (int)(ws_size / (8 * sizeof(float)));
    if (nb < 1) nb = 1;

    float* partials = (float*)d_ws;

    pvd_reduce_kernel<<<nb, 256, 0, stream>>>(act, W4, pd, tw, partials, N);
    pvd_finalize_kernel<<<1, 256, 0, stream>>>(partials, nb, Cw, inh, out);
}